// Round 1
// baseline (974.217 us; speedup 1.0000x reference)
//
#include <hip/hip_runtime.h>

// GCN encoder: 2x (GEMM -> gather/scatter-add over edges -> +b -> LN -> ReLU) -> L2 norm.
// N=50000 nodes, E=800000 edges, IN=128, HID=128, OUT=64.

#define K_DIM 128

// ---------- degree / dinv ----------
__global__ __launch_bounds__(256) void init_deg_kernel(float* deg, int n) {
    int i = blockIdx.x * 256 + threadIdx.x;
    if (i < n) deg[i] = 1.0f;  // self-loop
}

__global__ __launch_bounds__(256) void deg_accum_kernel(const int* __restrict__ dst,
                                                        float* deg, int E) {
    int i = blockIdx.x * 256 + threadIdx.x;
    if (i < E) atomicAdd(&deg[dst[i]], 1.0f);
}

__global__ __launch_bounds__(256) void dinv_kernel(float* deg, int n) {
    int i = blockIdx.x * 256 + threadIdx.x;
    if (i < n) deg[i] = rsqrtf(deg[i]);  // deg >= 1 always (self-loop)
}

// ---------- GEMM: H = X @ W  (X: [N][128], W: [128][COLS]) ----------
// Also writes AGG = H * dinv[row]^2  (self-loop contribution, seeds the scatter).
// Register tile 4 rows x 4 cols per thread; X tile staged in LDS (row-major, +4 pad).
template <int COLS>
__global__ __launch_bounds__(256) void gemm_kernel(const float* __restrict__ X,
                                                   const float* __restrict__ W,
                                                   const float* __restrict__ dinv,
                                                   float* __restrict__ H,
                                                   float* __restrict__ AGG, int N) {
    constexpr int CG = COLS / 4;       // col-groups (threads along cols)
    constexpr int RG = 256 / CG;       // row-groups
    constexpr int RT = RG * 4;         // rows per block
    __shared__ float xs[RT][K_DIM + 4];

    int row0 = blockIdx.x * RT;
    for (int idx = threadIdx.x; idx < RT * K_DIM; idx += 256) {
        int r = idx >> 7;          // / 128
        int c = idx & (K_DIM - 1); // % 128
        int row = row0 + r;
        xs[r][c] = (row < N) ? X[(size_t)row * K_DIM + c] : 0.0f;
    }
    __syncthreads();

    int cg = threadIdx.x % CG;
    int rg = threadIdx.x / CG;
    int col = cg * 4;

    float acc[4][4] = {};
    for (int k = 0; k < K_DIM; k += 4) {
        float4 xv0 = *(const float4*)&xs[rg * 4 + 0][k];
        float4 xv1 = *(const float4*)&xs[rg * 4 + 1][k];
        float4 xv2 = *(const float4*)&xs[rg * 4 + 2][k];
        float4 xv3 = *(const float4*)&xs[rg * 4 + 3][k];
#pragma unroll
        for (int kk = 0; kk < 4; ++kk) {
            float4 w = *(const float4*)(W + (size_t)(k + kk) * COLS + col);
            float x0 = (kk == 0) ? xv0.x : (kk == 1) ? xv0.y : (kk == 2) ? xv0.z : xv0.w;
            float x1 = (kk == 0) ? xv1.x : (kk == 1) ? xv1.y : (kk == 2) ? xv1.z : xv1.w;
            float x2 = (kk == 0) ? xv2.x : (kk == 1) ? xv2.y : (kk == 2) ? xv2.z : xv2.w;
            float x3 = (kk == 0) ? xv3.x : (kk == 1) ? xv3.y : (kk == 2) ? xv3.z : xv3.w;
            acc[0][0] = fmaf(x0, w.x, acc[0][0]); acc[0][1] = fmaf(x0, w.y, acc[0][1]);
            acc[0][2] = fmaf(x0, w.z, acc[0][2]); acc[0][3] = fmaf(x0, w.w, acc[0][3]);
            acc[1][0] = fmaf(x1, w.x, acc[1][0]); acc[1][1] = fmaf(x1, w.y, acc[1][1]);
            acc[1][2] = fmaf(x1, w.z, acc[1][2]); acc[1][3] = fmaf(x1, w.w, acc[1][3]);
            acc[2][0] = fmaf(x2, w.x, acc[2][0]); acc[2][1] = fmaf(x2, w.y, acc[2][1]);
            acc[2][2] = fmaf(x2, w.z, acc[2][2]); acc[2][3] = fmaf(x2, w.w, acc[2][3]);
            acc[3][0] = fmaf(x3, w.x, acc[3][0]); acc[3][1] = fmaf(x3, w.y, acc[3][1]);
            acc[3][2] = fmaf(x3, w.z, acc[3][2]); acc[3][3] = fmaf(x3, w.w, acc[3][3]);
        }
    }

#pragma unroll
    for (int r = 0; r < 4; ++r) {
        int row = row0 + rg * 4 + r;
        if (row < N) {
            float d = dinv[row];
            float dd = d * d;
            size_t base = (size_t)row * COLS + col;
#pragma unroll
            for (int j = 0; j < 4; ++j) {
                float v = acc[r][j];
                H[base + j]   = v;
                AGG[base + j] = v * dd;
            }
        }
    }
}

// ---------- edge scatter: agg[dst] += h[src] * dinv[src]*dinv[dst] ----------
// One wave (64 lanes) per edge. Layer 1: 128 ch (float2/lane). Layer 2: 64 ch.
__global__ __launch_bounds__(256) void scatter128_kernel(const float* __restrict__ h,
                                                         const float* __restrict__ dinv,
                                                         const int* __restrict__ src,
                                                         const int* __restrict__ dst,
                                                         float* agg, int E) {
    int wid = (blockIdx.x * 256 + threadIdx.x) >> 6;
    int lane = threadIdx.x & 63;
    if (wid >= E) return;
    int s = src[wid], d = dst[wid];
    float w = dinv[s] * dinv[d];
    float2 v = ((const float2*)(h + (size_t)s * 128))[lane];
    float* a = agg + (size_t)d * 128 + lane * 2;
    atomicAdd(a,     v.x * w);
    atomicAdd(a + 1, v.y * w);
}

__global__ __launch_bounds__(256) void scatter64_kernel(const float* __restrict__ h,
                                                        const float* __restrict__ dinv,
                                                        const int* __restrict__ src,
                                                        const int* __restrict__ dst,
                                                        float* agg, int E) {
    int wid = (blockIdx.x * 256 + threadIdx.x) >> 6;
    int lane = threadIdx.x & 63;
    if (wid >= E) return;
    int s = src[wid], d = dst[wid];
    float w = dinv[s] * dinv[d];
    float v = h[(size_t)s * 64 + lane] * w;
    atomicAdd(&agg[(size_t)d * 64 + lane], v);
}

// ---------- LayerNorm + ReLU (128 ch), wave per node ----------
__global__ __launch_bounds__(256) void ln_relu128_kernel(const float* __restrict__ agg,
                                                         const float* __restrict__ b,
                                                         const float* __restrict__ g,
                                                         const float* __restrict__ beta,
                                                         float* __restrict__ out, int N) {
    int node = (blockIdx.x * 256 + threadIdx.x) >> 6;
    int lane = threadIdx.x & 63;
    if (node >= N) return;
    float2 v = ((const float2*)(agg + (size_t)node * 128))[lane];
    float2 bb = ((const float2*)b)[lane];
    v.x += bb.x; v.y += bb.y;
    float s = v.x + v.y;
    for (int off = 32; off; off >>= 1) s += __shfl_xor(s, off);
    float mu = s * (1.0f / 128.0f);
    float dx = v.x - mu, dy = v.y - mu;
    float q = dx * dx + dy * dy;
    for (int off = 32; off; off >>= 1) q += __shfl_xor(q, off);
    float rstd = rsqrtf(q * (1.0f / 128.0f) + 1e-5f);
    float2 gg = ((const float2*)g)[lane];
    float2 be = ((const float2*)beta)[lane];
    float ox = fmaxf(fmaf(dx * rstd, gg.x, be.x), 0.0f);
    float oy = fmaxf(fmaf(dy * rstd, gg.y, be.y), 0.0f);
    ((float2*)(out + (size_t)node * 128))[lane] = make_float2(ox, oy);
}

// ---------- LayerNorm + ReLU + L2 normalize (64 ch), wave per node ----------
__global__ __launch_bounds__(256) void ln_l2_64_kernel(const float* __restrict__ agg,
                                                       const float* __restrict__ b,
                                                       const float* __restrict__ g,
                                                       const float* __restrict__ beta,
                                                       float* __restrict__ out, int N) {
    int node = (blockIdx.x * 256 + threadIdx.x) >> 6;
    int lane = threadIdx.x & 63;
    if (node >= N) return;
    float v = agg[(size_t)node * 64 + lane] + b[lane];
    float s = v;
    for (int off = 32; off; off >>= 1) s += __shfl_xor(s, off);
    float mu = s * (1.0f / 64.0f);
    float d = v - mu;
    float q = d * d;
    for (int off = 32; off; off >>= 1) q += __shfl_xor(q, off);
    float rstd = rsqrtf(q * (1.0f / 64.0f) + 1e-5f);
    float o = fmaxf(fmaf(d * rstd, g[lane], beta[lane]), 0.0f);
    float q2 = o * o;
    for (int off = 32; off; off >>= 1) q2 += __shfl_xor(q2, off);
    float nrm = sqrtf(q2);
    out[(size_t)node * 64 + lane] = o / fmaxf(nrm, 1e-12f);
}

extern "C" void kernel_launch(void* const* d_in, const int* in_sizes, int n_in,
                              void* d_out, int out_size, void* d_ws, size_t ws_size,
                              hipStream_t stream) {
    const float* x     = (const float*)d_in[0];
    const int*   ei    = (const int*)d_in[1];
    const float* W1    = (const float*)d_in[2];
    const float* b1    = (const float*)d_in[3];
    const float* g1    = (const float*)d_in[4];
    const float* beta1 = (const float*)d_in[5];
    const float* W2    = (const float*)d_in[6];
    const float* b2    = (const float*)d_in[7];
    const float* g2    = (const float*)d_in[8];
    const float* beta2 = (const float*)d_in[9];

    const int N = in_sizes[0] / 128;
    const int E = in_sizes[1] / 2;
    const int* src = ei;       // edge_index[0]
    const int* dst = ei + E;   // edge_index[1]
    float* out = (float*)d_out;

    // Workspace layout (floats):
    //   dinv  : N            (deg computed in place, then rsqrt'ed)
    //   bufA  : N*128        (h1; reused as h2 after scatter1)
    //   bufB  : N*128        (agg1; reused as h3 [N*64] + agg2 [N*64] for layer 2)
    float* ws   = (float*)d_ws;
    float* dinv = ws;
    float* bufA = ws + (((size_t)N + 255) & ~(size_t)255);
    float* bufB = bufA + (size_t)N * 128;
    float* h1   = bufA;
    float* agg1 = bufB;
    float* h2   = bufA;                    // overwrites h1 (dead after scatter1)
    float* h3   = bufB;                    // overwrites agg1 (dead after ln_relu1)
    float* agg2 = bufB + (size_t)N * 64;

    const int nb_nodes = (N + 255) / 256;
    const int nb_edges = (E + 255) / 256;
    const int nb_wave_edges = (E + 3) / 4;    // 4 waves of 64 per 256-block
    const int nb_wave_nodes = (N + 3) / 4;

    // degree -> dinv
    init_deg_kernel<<<nb_nodes, 256, 0, stream>>>(dinv, N);
    deg_accum_kernel<<<nb_edges, 256, 0, stream>>>(dst, dinv, E);
    dinv_kernel<<<nb_nodes, 256, 0, stream>>>(dinv, N);

    // layer 1
    gemm_kernel<128><<<(N + 31) / 32, 256, 0, stream>>>(x, W1, dinv, h1, agg1, N);
    scatter128_kernel<<<nb_wave_edges, 256, 0, stream>>>(h1, dinv, src, dst, agg1, E);
    ln_relu128_kernel<<<nb_wave_nodes, 256, 0, stream>>>(agg1, b1, g1, beta1, h2, N);

    // layer 2
    gemm_kernel<64><<<(N + 63) / 64, 256, 0, stream>>>(h2, W2, dinv, h3, agg2, N);
    scatter64_kernel<<<nb_wave_edges, 256, 0, stream>>>(h3, dinv, src, dst, agg2, E);
    ln_l2_64_kernel<<<nb_wave_nodes, 256, 0, stream>>>(agg2, b2, g2, beta2, out, N);
}

// Round 2
// 339.635 us; speedup vs baseline: 2.8684x; 2.8684x over previous
//
#include <hip/hip_runtime.h>

// GCN encoder on MI355X. Strategy: counting-sort edges by dst into CSR, then
// gather-based aggregation (wave per node) with fused bias+LN+ReLU epilogues.
// Layer-2 GEMM (128x64 matvec) is fused into gather1's epilogue via LDS.

#define K_DIM 128

// ---------- CSR build ----------
__global__ __launch_bounds__(256) void zero_counts_kernel(int* counts, int n) {
    int i = blockIdx.x * 256 + threadIdx.x;
    if (i < n) counts[i] = 0;
}

__global__ __launch_bounds__(256) void hist_kernel(const int* __restrict__ dst,
                                                   int* counts, int E) {
    int i = blockIdx.x * 256 + threadIdx.x;
    if (i < E) atomicAdd(&counts[dst[i]], 1);
}

__global__ __launch_bounds__(256) void dinv_kernel(const int* __restrict__ counts,
                                                   float* dinv, int n) {
    int i = blockIdx.x * 256 + threadIdx.x;
    if (i < n) dinv[i] = rsqrtf((float)(counts[i] + 1));  // +1 self-loop
}

// exclusive scan of counts -> row_ptr, chunk of 256 per block; partials[b] = chunk total
__global__ __launch_bounds__(256) void scan_block_kernel(const int* __restrict__ counts,
                                                         int* row_ptr, int* partials, int N) {
    __shared__ int sm[256];
    int t = threadIdx.x;
    int i = blockIdx.x * 256 + t;
    int v = (i < N) ? counts[i] : 0;
    sm[t] = v;
    __syncthreads();
    for (int off = 1; off < 256; off <<= 1) {
        int add = (t >= off) ? sm[t - off] : 0;
        __syncthreads();
        sm[t] += add;
        __syncthreads();
    }
    if (i < N) row_ptr[i] = sm[t] - v;  // exclusive
    if (t == 255) partials[blockIdx.x] = sm[255];
}

__global__ __launch_bounds__(256) void scan_partials_kernel(int* partials, int NB) {
    __shared__ int sm[256];
    int t = threadIdx.x;
    int v = (t < NB) ? partials[t] : 0;
    sm[t] = v;
    __syncthreads();
    for (int off = 1; off < 256; off <<= 1) {
        int add = (t >= off) ? sm[t - off] : 0;
        __syncthreads();
        sm[t] += add;
        __syncthreads();
    }
    if (t < NB) partials[t] = sm[t] - v;  // exclusive
}

__global__ __launch_bounds__(256) void scan_add_kernel(int* row_ptr, const int* __restrict__ partials,
                                                       int N) {
    int i = blockIdx.x * 256 + threadIdx.x;
    if (i < N) row_ptr[i] += partials[blockIdx.x];
}

// fill: row_ptr[d] is used as a cursor; after this kernel row_ptr[d] == row END.
// gather uses  start = row_ptr[d] - counts[d].
__global__ __launch_bounds__(256) void fill_kernel(const int* __restrict__ src,
                                                   const int* __restrict__ dst,
                                                   int* row_ptr, int* sorted_src, int E) {
    int i = blockIdx.x * 256 + threadIdx.x;
    if (i < E) {
        int d = dst[i];
        int pos = atomicAdd(&row_ptr[d], 1);
        sorted_src[pos] = src[i];
    }
}

// ---------- GEMM1: H = X @ W1  (X: [N][128], W1: [128][128]) ----------
__global__ __launch_bounds__(256) void gemm1_kernel(const float* __restrict__ X,
                                                    const float* __restrict__ W,
                                                    float* __restrict__ H, int N) {
    constexpr int COLS = 128;
    constexpr int CG = COLS / 4;       // 32 col-groups
    constexpr int RG = 256 / CG;       // 8 row-groups
    constexpr int RT = RG * 4;         // 32 rows per block
    __shared__ float xs[RT][K_DIM + 4];

    int row0 = blockIdx.x * RT;
    for (int idx = threadIdx.x; idx < RT * K_DIM; idx += 256) {
        int r = idx >> 7;
        int c = idx & (K_DIM - 1);
        int row = row0 + r;
        xs[r][c] = (row < N) ? X[(size_t)row * K_DIM + c] : 0.0f;
    }
    __syncthreads();

    int cg = threadIdx.x % CG;
    int rg = threadIdx.x / CG;
    int col = cg * 4;

    float acc[4][4] = {};
    for (int k = 0; k < K_DIM; k += 4) {
        float4 xv0 = *(const float4*)&xs[rg * 4 + 0][k];
        float4 xv1 = *(const float4*)&xs[rg * 4 + 1][k];
        float4 xv2 = *(const float4*)&xs[rg * 4 + 2][k];
        float4 xv3 = *(const float4*)&xs[rg * 4 + 3][k];
#pragma unroll
        for (int kk = 0; kk < 4; ++kk) {
            float4 w = *(const float4*)(W + (size_t)(k + kk) * COLS + col);
            float x0 = (kk == 0) ? xv0.x : (kk == 1) ? xv0.y : (kk == 2) ? xv0.z : xv0.w;
            float x1 = (kk == 0) ? xv1.x : (kk == 1) ? xv1.y : (kk == 2) ? xv1.z : xv1.w;
            float x2 = (kk == 0) ? xv2.x : (kk == 1) ? xv2.y : (kk == 2) ? xv2.z : xv2.w;
            float x3 = (kk == 0) ? xv3.x : (kk == 1) ? xv3.y : (kk == 2) ? xv3.z : xv3.w;
            acc[0][0] = fmaf(x0, w.x, acc[0][0]); acc[0][1] = fmaf(x0, w.y, acc[0][1]);
            acc[0][2] = fmaf(x0, w.z, acc[0][2]); acc[0][3] = fmaf(x0, w.w, acc[0][3]);
            acc[1][0] = fmaf(x1, w.x, acc[1][0]); acc[1][1] = fmaf(x1, w.y, acc[1][1]);
            acc[1][2] = fmaf(x1, w.z, acc[1][2]); acc[1][3] = fmaf(x1, w.w, acc[1][3]);
            acc[2][0] = fmaf(x2, w.x, acc[2][0]); acc[2][1] = fmaf(x2, w.y, acc[2][1]);
            acc[2][2] = fmaf(x2, w.z, acc[2][2]); acc[2][3] = fmaf(x2, w.w, acc[2][3]);
            acc[3][0] = fmaf(x3, w.x, acc[3][0]); acc[3][1] = fmaf(x3, w.y, acc[3][1]);
            acc[3][2] = fmaf(x3, w.z, acc[3][2]); acc[3][3] = fmaf(x3, w.w, acc[3][3]);
        }
    }

#pragma unroll
    for (int r = 0; r < 4; ++r) {
        int row = row0 + rg * 4 + r;
        if (row < N) {
            size_t base = (size_t)row * COLS + col;
#pragma unroll
            for (int j = 0; j < 4; ++j) H[base + j] = acc[r][j];
        }
    }
}

// ---------- gather1 fused: agg -> +b1 -> LN -> ReLU -> (@W2) -> h3 ----------
// One wave per node; 128 ch as float2/lane. Then 128x64 matvec via LDS broadcast.
__global__ __launch_bounds__(256) void gather1_fused_kernel(
    const float* __restrict__ h1, const float* __restrict__ dinv,
    const int* __restrict__ row_ptr, const int* __restrict__ counts,
    const int* __restrict__ sorted_src,
    const float* __restrict__ b1, const float* __restrict__ g1,
    const float* __restrict__ beta1, const float* __restrict__ W2,
    float* __restrict__ h3, int N) {
    __shared__ float lds[4][K_DIM];
    int wave = threadIdx.x >> 6;
    int lane = threadIdx.x & 63;
    int node = blockIdx.x * 4 + wave;
    if (node >= N) return;

    float dd = dinv[node];
    // self-loop seed
    float2 acc = ((const float2*)(h1 + (size_t)node * 128))[lane];
    acc.x *= dd * dd; acc.y *= dd * dd;

    int end = row_ptr[node];
    int cnt = counts[node];
    for (int e = end - cnt; e < end; ++e) {
        int s = sorted_src[e];
        float w = dinv[s] * dd;
        float2 v = ((const float2*)(h1 + (size_t)s * 128))[lane];
        acc.x = fmaf(v.x, w, acc.x);
        acc.y = fmaf(v.y, w, acc.y);
    }

    // bias + LN + ReLU
    float2 bb = ((const float2*)b1)[lane];
    acc.x += bb.x; acc.y += bb.y;
    float s = acc.x + acc.y;
    for (int off = 32; off; off >>= 1) s += __shfl_xor(s, off);
    float mu = s * (1.0f / 128.0f);
    float dx = acc.x - mu, dy = acc.y - mu;
    float q = dx * dx + dy * dy;
    for (int off = 32; off; off >>= 1) q += __shfl_xor(q, off);
    float rstd = rsqrtf(q * (1.0f / 128.0f) + 1e-5f);
    float2 gg = ((const float2*)g1)[lane];
    float2 be = ((const float2*)beta1)[lane];
    float ox = fmaxf(fmaf(dx * rstd, gg.x, be.x), 0.0f);
    float oy = fmaxf(fmaf(dy * rstd, gg.y, be.y), 0.0f);

    // stage the 128-vector in LDS, then matvec with W2 [128][64]; lane owns col=lane
    ((float2*)&lds[wave][0])[lane] = make_float2(ox, oy);
    float o = 0.0f;
#pragma unroll 8
    for (int k = 0; k < K_DIM; k += 4) {
        float4 vv = *(const float4*)&lds[wave][k];          // broadcast read
        o = fmaf(vv.x, W2[(size_t)(k + 0) * 64 + lane], o);
        o = fmaf(vv.y, W2[(size_t)(k + 1) * 64 + lane], o);
        o = fmaf(vv.z, W2[(size_t)(k + 2) * 64 + lane], o);
        o = fmaf(vv.w, W2[(size_t)(k + 3) * 64 + lane], o);
    }
    h3[(size_t)node * 64 + lane] = o;
}

// ---------- gather2 fused: agg -> +b2 -> LN -> ReLU -> L2 normalize -> out ----------
__global__ __launch_bounds__(256) void gather2_fused_kernel(
    const float* __restrict__ h3, const float* __restrict__ dinv,
    const int* __restrict__ row_ptr, const int* __restrict__ counts,
    const int* __restrict__ sorted_src,
    const float* __restrict__ b2, const float* __restrict__ g2,
    const float* __restrict__ beta2, float* __restrict__ out, int N) {
    int wave = threadIdx.x >> 6;
    int lane = threadIdx.x & 63;
    int node = blockIdx.x * 4 + wave;
    if (node >= N) return;

    float dd = dinv[node];
    float acc = h3[(size_t)node * 64 + lane] * dd * dd;

    int end = row_ptr[node];
    int cnt = counts[node];
    for (int e = end - cnt; e < end; ++e) {
        int s = sorted_src[e];
        float w = dinv[s] * dd;
        acc = fmaf(h3[(size_t)s * 64 + lane], w, acc);
    }

    float v = acc + b2[lane];
    float s = v;
    for (int off = 32; off; off >>= 1) s += __shfl_xor(s, off);
    float mu = s * (1.0f / 64.0f);
    float d = v - mu;
    float q = d * d;
    for (int off = 32; off; off >>= 1) q += __shfl_xor(q, off);
    float rstd = rsqrtf(q * (1.0f / 64.0f) + 1e-5f);
    float o = fmaxf(fmaf(d * rstd, g2[lane], beta2[lane]), 0.0f);
    float q2 = o * o;
    for (int off = 32; off; off >>= 1) q2 += __shfl_xor(q2, off);
    float nrm = sqrtf(q2);
    out[(size_t)node * 64 + lane] = o / fmaxf(nrm, 1e-12f);
}

extern "C" void kernel_launch(void* const* d_in, const int* in_sizes, int n_in,
                              void* d_out, int out_size, void* d_ws, size_t ws_size,
                              hipStream_t stream) {
    const float* x     = (const float*)d_in[0];
    const int*   ei    = (const int*)d_in[1];
    const float* W1    = (const float*)d_in[2];
    const float* b1    = (const float*)d_in[3];
    const float* g1    = (const float*)d_in[4];
    const float* beta1 = (const float*)d_in[5];
    const float* W2    = (const float*)d_in[6];
    const float* b2    = (const float*)d_in[7];
    const float* g2    = (const float*)d_in[8];
    const float* beta2 = (const float*)d_in[9];

    const int N = in_sizes[0] / 128;
    const int E = in_sizes[1] / 2;
    const int* src = ei;       // edge_index[0]
    const int* dst = ei + E;   // edge_index[1]
    float* out = (float*)d_out;

    // Workspace layout (peak ~42.3 MB):
    //   counts     : N ints
    //   row_ptr    : N ints  (becomes row-end after fill)
    //   partials   : 256 ints
    //   dinv       : N floats
    //   sorted_src : E ints
    //   h1         : N*128 floats (25.6 MB)
    //   h3         : N*64  floats (12.8 MB)
    char* p = (char*)d_ws;
    auto alloc = [&](size_t bytes) { char* r = p; p += (bytes + 255) & ~(size_t)255; return r; };
    int*   counts     = (int*)alloc((size_t)N * 4);
    int*   row_ptr    = (int*)alloc((size_t)N * 4);
    int*   partials   = (int*)alloc(256 * 4);
    float* dinv       = (float*)alloc((size_t)N * 4);
    int*   sorted_src = (int*)alloc((size_t)E * 4);
    float* h1         = (float*)alloc((size_t)N * 128 * 4);
    float* h3         = (float*)alloc((size_t)N * 64 * 4);

    const int nb_nodes = (N + 255) / 256;   // 196 blocks (also the scan chunk count)
    const int nb_edges = (E + 255) / 256;
    const int nb_wave_nodes = (N + 3) / 4;

    // CSR build + dinv
    zero_counts_kernel<<<nb_nodes, 256, 0, stream>>>(counts, N);
    hist_kernel<<<nb_edges, 256, 0, stream>>>(dst, counts, E);
    dinv_kernel<<<nb_nodes, 256, 0, stream>>>(counts, dinv, N);
    scan_block_kernel<<<nb_nodes, 256, 0, stream>>>(counts, row_ptr, partials, N);
    scan_partials_kernel<<<1, 256, 0, stream>>>(partials, nb_nodes);
    scan_add_kernel<<<nb_nodes, 256, 0, stream>>>(row_ptr, partials, N);
    fill_kernel<<<nb_edges, 256, 0, stream>>>(src, dst, row_ptr, sorted_src, E);

    // layer 1 GEMM
    gemm1_kernel<<<(N + 31) / 32, 256, 0, stream>>>(x, W1, h1, N);

    // layer 1 aggregate + LN + ReLU + layer 2 GEMM (fused)
    gather1_fused_kernel<<<nb_wave_nodes, 256, 0, stream>>>(
        h1, dinv, row_ptr, counts, sorted_src, b1, g1, beta1, W2, h3, N);

    // layer 2 aggregate + LN + ReLU + L2 (fused)
    gather2_fused_kernel<<<nb_wave_nodes, 256, 0, stream>>>(
        h3, dinv, row_ptr, counts, sorted_src, b2, g2, beta2, out, N);
}

// Round 3
// 254.762 us; speedup vs baseline: 3.8240x; 1.3331x over previous
//
#include <hip/hip_runtime.h>
#include <hip/hip_fp16.h>

// GCN encoder on MI355X. CSR (counting sort by dst) + gather aggregation.
// Hidden activations h1/h3 stored as fp16 to halve random-gather traffic;
// per-edge norm weights precomputed at fill time; gather loop unrolled 4x
// for memory-level parallelism. Epilogues fused (bias+LN+ReLU, W2 matvec, L2).

#define K_DIM 128

// ---------- CSR build ----------
__global__ __launch_bounds__(256) void hist_kernel(const int* __restrict__ dst,
                                                   int* counts, int E) {
    int i = blockIdx.x * 256 + threadIdx.x;
    if (i < E) atomicAdd(&counts[dst[i]], 1);
}

__global__ __launch_bounds__(256) void dinv_kernel(const int* __restrict__ counts,
                                                   float* dinv, int n) {
    int i = blockIdx.x * 256 + threadIdx.x;
    if (i < n) dinv[i] = rsqrtf((float)(counts[i] + 1));  // +1 self-loop
}

__global__ __launch_bounds__(256) void scan_block_kernel(const int* __restrict__ counts,
                                                         int* row_ptr, int* partials, int N) {
    __shared__ int sm[256];
    int t = threadIdx.x;
    int i = blockIdx.x * 256 + t;
    int v = (i < N) ? counts[i] : 0;
    sm[t] = v;
    __syncthreads();
    for (int off = 1; off < 256; off <<= 1) {
        int add = (t >= off) ? sm[t - off] : 0;
        __syncthreads();
        sm[t] += add;
        __syncthreads();
    }
    if (i < N) row_ptr[i] = sm[t] - v;  // exclusive
    if (t == 255) partials[blockIdx.x] = sm[255];
}

__global__ __launch_bounds__(256) void scan_partials_kernel(int* partials, int NB) {
    __shared__ int sm[256];
    int t = threadIdx.x;
    int v = (t < NB) ? partials[t] : 0;
    sm[t] = v;
    __syncthreads();
    for (int off = 1; off < 256; off <<= 1) {
        int add = (t >= off) ? sm[t - off] : 0;
        __syncthreads();
        sm[t] += add;
        __syncthreads();
    }
    if (t < NB) partials[t] = sm[t] - v;  // exclusive
}

__global__ __launch_bounds__(256) void scan_add_kernel(int* row_ptr, const int* __restrict__ partials,
                                                       int N) {
    int i = blockIdx.x * 256 + threadIdx.x;
    if (i < N) row_ptr[i] += partials[blockIdx.x];
}

// fill: row_ptr[d] used as cursor; afterwards row_ptr[d] == row END.
// Also precomputes edge weight dinv[s]*dinv[d] (shared by both layers).
__global__ __launch_bounds__(256) void fill_kernel(const int* __restrict__ src,
                                                   const int* __restrict__ dst,
                                                   const float* __restrict__ dinv,
                                                   int* row_ptr, int* sorted_src,
                                                   float* edge_w, int E) {
    int i = blockIdx.x * 256 + threadIdx.x;
    if (i < E) {
        int d = dst[i];
        int s = src[i];
        int pos = atomicAdd(&row_ptr[d], 1);
        sorted_src[pos] = s;
        edge_w[pos] = dinv[s] * dinv[d];
    }
}

// ---------- GEMM1: H = X @ W1 (fp32 in, fp16 out) ----------
__global__ __launch_bounds__(256) void gemm1_kernel(const float* __restrict__ X,
                                                    const float* __restrict__ W,
                                                    __half* __restrict__ H, int N) {
    constexpr int COLS = 128;
    constexpr int CG = COLS / 4;       // 32 col-groups
    constexpr int RG = 256 / CG;       // 8 row-groups
    constexpr int RT = RG * 4;         // 32 rows per block
    __shared__ float xs[RT][K_DIM + 4];

    int row0 = blockIdx.x * RT;
    for (int idx = threadIdx.x; idx < RT * K_DIM; idx += 256) {
        int r = idx >> 7;
        int c = idx & (K_DIM - 1);
        int row = row0 + r;
        xs[r][c] = (row < N) ? X[(size_t)row * K_DIM + c] : 0.0f;
    }
    __syncthreads();

    int cg = threadIdx.x % CG;
    int rg = threadIdx.x / CG;
    int col = cg * 4;

    float acc[4][4] = {};
    for (int k = 0; k < K_DIM; k += 4) {
        float4 xv0 = *(const float4*)&xs[rg * 4 + 0][k];
        float4 xv1 = *(const float4*)&xs[rg * 4 + 1][k];
        float4 xv2 = *(const float4*)&xs[rg * 4 + 2][k];
        float4 xv3 = *(const float4*)&xs[rg * 4 + 3][k];
#pragma unroll
        for (int kk = 0; kk < 4; ++kk) {
            float4 w = *(const float4*)(W + (size_t)(k + kk) * COLS + col);
            float x0 = (kk == 0) ? xv0.x : (kk == 1) ? xv0.y : (kk == 2) ? xv0.z : xv0.w;
            float x1 = (kk == 0) ? xv1.x : (kk == 1) ? xv1.y : (kk == 2) ? xv1.z : xv1.w;
            float x2 = (kk == 0) ? xv2.x : (kk == 1) ? xv2.y : (kk == 2) ? xv2.z : xv2.w;
            float x3 = (kk == 0) ? xv3.x : (kk == 1) ? xv3.y : (kk == 2) ? xv3.z : xv3.w;
            acc[0][0] = fmaf(x0, w.x, acc[0][0]); acc[0][1] = fmaf(x0, w.y, acc[0][1]);
            acc[0][2] = fmaf(x0, w.z, acc[0][2]); acc[0][3] = fmaf(x0, w.w, acc[0][3]);
            acc[1][0] = fmaf(x1, w.x, acc[1][0]); acc[1][1] = fmaf(x1, w.y, acc[1][1]);
            acc[1][2] = fmaf(x1, w.z, acc[1][2]); acc[1][3] = fmaf(x1, w.w, acc[1][3]);
            acc[2][0] = fmaf(x2, w.x, acc[2][0]); acc[2][1] = fmaf(x2, w.y, acc[2][1]);
            acc[2][2] = fmaf(x2, w.z, acc[2][2]); acc[2][3] = fmaf(x2, w.w, acc[2][3]);
            acc[3][0] = fmaf(x3, w.x, acc[3][0]); acc[3][1] = fmaf(x3, w.y, acc[3][1]);
            acc[3][2] = fmaf(x3, w.z, acc[3][2]); acc[3][3] = fmaf(x3, w.w, acc[3][3]);
        }
    }

#pragma unroll
    for (int r = 0; r < 4; ++r) {
        int row = row0 + rg * 4 + r;
        if (row < N) {
            __half2* o2 = (__half2*)(H + (size_t)row * COLS + col);
            o2[0] = __float22half2_rn(make_float2(acc[r][0], acc[r][1]));
            o2[1] = __float22half2_rn(make_float2(acc[r][2], acc[r][3]));
        }
    }
}

// ---------- gather1 fused: agg(h1) -> +b1 -> LN -> ReLU -> @W2 -> h3 (fp16) ----------
__global__ __launch_bounds__(256) void gather1_fused_kernel(
    const __half* __restrict__ h1, const float* __restrict__ dinv,
    const int* __restrict__ row_ptr, const int* __restrict__ counts,
    const int* __restrict__ sorted_src, const float* __restrict__ edge_w,
    const float* __restrict__ b1, const float* __restrict__ g1,
    const float* __restrict__ beta1, const float* __restrict__ W2,
    __half* __restrict__ h3, int N) {
    __shared__ float lds[4][K_DIM];
    int wave = threadIdx.x >> 6;
    int lane = threadIdx.x & 63;
    int node = blockIdx.x * 4 + wave;
    if (node >= N) return;

    float dd = dinv[node];
    // self-loop seed
    float2 acc = __half22float2(((const __half2*)(h1 + (size_t)node * 128))[lane]);
    acc.x *= dd * dd; acc.y *= dd * dd;

    int end = row_ptr[node];
    int beg = end - counts[node];
    int e = beg;
    for (; e + 4 <= end; e += 4) {
        int s0 = sorted_src[e],     s1 = sorted_src[e + 1];
        int s2 = sorted_src[e + 2], s3 = sorted_src[e + 3];
        float w0 = edge_w[e],     w1 = edge_w[e + 1];
        float w2 = edge_w[e + 2], w3 = edge_w[e + 3];
        __half2 v0 = ((const __half2*)(h1 + (size_t)s0 * 128))[lane];
        __half2 v1 = ((const __half2*)(h1 + (size_t)s1 * 128))[lane];
        __half2 v2 = ((const __half2*)(h1 + (size_t)s2 * 128))[lane];
        __half2 v3 = ((const __half2*)(h1 + (size_t)s3 * 128))[lane];
        float2 f0 = __half22float2(v0), f1 = __half22float2(v1);
        float2 f2 = __half22float2(v2), f3 = __half22float2(v3);
        acc.x = fmaf(f0.x, w0, acc.x); acc.y = fmaf(f0.y, w0, acc.y);
        acc.x = fmaf(f1.x, w1, acc.x); acc.y = fmaf(f1.y, w1, acc.y);
        acc.x = fmaf(f2.x, w2, acc.x); acc.y = fmaf(f2.y, w2, acc.y);
        acc.x = fmaf(f3.x, w3, acc.x); acc.y = fmaf(f3.y, w3, acc.y);
    }
    for (; e < end; ++e) {
        int s = sorted_src[e];
        float w = edge_w[e];
        float2 f = __half22float2(((const __half2*)(h1 + (size_t)s * 128))[lane]);
        acc.x = fmaf(f.x, w, acc.x);
        acc.y = fmaf(f.y, w, acc.y);
    }

    // bias + LN + ReLU
    float2 bb = ((const float2*)b1)[lane];
    acc.x += bb.x; acc.y += bb.y;
    float s = acc.x + acc.y;
    for (int off = 32; off; off >>= 1) s += __shfl_xor(s, off);
    float mu = s * (1.0f / 128.0f);
    float dx = acc.x - mu, dy = acc.y - mu;
    float q = dx * dx + dy * dy;
    for (int off = 32; off; off >>= 1) q += __shfl_xor(q, off);
    float rstd = rsqrtf(q * (1.0f / 128.0f) + 1e-5f);
    float2 gg = ((const float2*)g1)[lane];
    float2 be = ((const float2*)beta1)[lane];
    float ox = fmaxf(fmaf(dx * rstd, gg.x, be.x), 0.0f);
    float oy = fmaxf(fmaf(dy * rstd, gg.y, be.y), 0.0f);

    // 128x64 matvec via LDS broadcast; lane owns output col = lane
    ((float2*)&lds[wave][0])[lane] = make_float2(ox, oy);
    float o = 0.0f;
#pragma unroll 8
    for (int k = 0; k < K_DIM; k += 4) {
        float4 vv = *(const float4*)&lds[wave][k];
        o = fmaf(vv.x, W2[(size_t)(k + 0) * 64 + lane], o);
        o = fmaf(vv.y, W2[(size_t)(k + 1) * 64 + lane], o);
        o = fmaf(vv.z, W2[(size_t)(k + 2) * 64 + lane], o);
        o = fmaf(vv.w, W2[(size_t)(k + 3) * 64 + lane], o);
    }
    h3[(size_t)node * 64 + lane] = __float2half(o);
}

// ---------- gather2 fused: agg(h3) -> +b2 -> LN -> ReLU -> L2 -> out ----------
__global__ __launch_bounds__(256) void gather2_fused_kernel(
    const __half* __restrict__ h3, const float* __restrict__ dinv,
    const int* __restrict__ row_ptr, const int* __restrict__ counts,
    const int* __restrict__ sorted_src, const float* __restrict__ edge_w,
    const float* __restrict__ b2, const float* __restrict__ g2,
    const float* __restrict__ beta2, float* __restrict__ out, int N) {
    int wave = threadIdx.x >> 6;
    int lane = threadIdx.x & 63;
    int node = blockIdx.x * 4 + wave;
    if (node >= N) return;

    float dd = dinv[node];
    float acc = __half2float(h3[(size_t)node * 64 + lane]) * dd * dd;

    int end = row_ptr[node];
    int beg = end - counts[node];
    int e = beg;
    for (; e + 4 <= end; e += 4) {
        int s0 = sorted_src[e],     s1 = sorted_src[e + 1];
        int s2 = sorted_src[e + 2], s3 = sorted_src[e + 3];
        float w0 = edge_w[e],     w1 = edge_w[e + 1];
        float w2 = edge_w[e + 2], w3 = edge_w[e + 3];
        float f0 = __half2float(h3[(size_t)s0 * 64 + lane]);
        float f1 = __half2float(h3[(size_t)s1 * 64 + lane]);
        float f2 = __half2float(h3[(size_t)s2 * 64 + lane]);
        float f3 = __half2float(h3[(size_t)s3 * 64 + lane]);
        acc = fmaf(f0, w0, acc);
        acc = fmaf(f1, w1, acc);
        acc = fmaf(f2, w2, acc);
        acc = fmaf(f3, w3, acc);
    }
    for (; e < end; ++e) {
        acc = fmaf(__half2float(h3[(size_t)sorted_src[e] * 64 + lane]), edge_w[e], acc);
    }

    float v = acc + b2[lane];
    float s = v;
    for (int off = 32; off; off >>= 1) s += __shfl_xor(s, off);
    float mu = s * (1.0f / 64.0f);
    float d = v - mu;
    float q = d * d;
    for (int off = 32; off; off >>= 1) q += __shfl_xor(q, off);
    float rstd = rsqrtf(q * (1.0f / 64.0f) + 1e-5f);
    float o = fmaxf(fmaf(d * rstd, g2[lane], beta2[lane]), 0.0f);
    float q2 = o * o;
    for (int off = 32; off; off >>= 1) q2 += __shfl_xor(q2, off);
    float nrm = sqrtf(q2);
    out[(size_t)node * 64 + lane] = o / fmaxf(nrm, 1e-12f);
}

extern "C" void kernel_launch(void* const* d_in, const int* in_sizes, int n_in,
                              void* d_out, int out_size, void* d_ws, size_t ws_size,
                              hipStream_t stream) {
    const float* x     = (const float*)d_in[0];
    const int*   ei    = (const int*)d_in[1];
    const float* W1    = (const float*)d_in[2];
    const float* b1    = (const float*)d_in[3];
    const float* g1    = (const float*)d_in[4];
    const float* beta1 = (const float*)d_in[5];
    const float* W2    = (const float*)d_in[6];
    const float* b2    = (const float*)d_in[7];
    const float* g2    = (const float*)d_in[8];
    const float* beta2 = (const float*)d_in[9];

    const int N = in_sizes[0] / 128;
    const int E = in_sizes[1] / 2;
    const int* src = ei;       // edge_index[0]
    const int* dst = ei + E;   // edge_index[1]
    float* out = (float*)d_out;

    // Workspace layout (~26 MB):
    char* p = (char*)d_ws;
    auto alloc = [&](size_t bytes) { char* r = p; p += (bytes + 255) & ~(size_t)255; return r; };
    int*    counts     = (int*)alloc((size_t)N * 4);
    int*    row_ptr    = (int*)alloc((size_t)N * 4);
    int*    partials   = (int*)alloc(256 * 4);
    float*  dinv       = (float*)alloc((size_t)N * 4);
    int*    sorted_src = (int*)alloc((size_t)E * 4);
    float*  edge_w     = (float*)alloc((size_t)E * 4);
    __half* h1         = (__half*)alloc((size_t)N * 128 * 2);
    __half* h3         = (__half*)alloc((size_t)N * 64 * 2);

    const int nb_nodes = (N + 255) / 256;
    const int nb_edges = (E + 255) / 256;
    const int nb_wave_nodes = (N + 3) / 4;

    // CSR build + dinv + per-edge weights
    hipMemsetAsync(counts, 0, (size_t)N * 4, stream);
    hist_kernel<<<nb_edges, 256, 0, stream>>>(dst, counts, E);
    dinv_kernel<<<nb_nodes, 256, 0, stream>>>(counts, dinv, N);
    scan_block_kernel<<<nb_nodes, 256, 0, stream>>>(counts, row_ptr, partials, N);
    scan_partials_kernel<<<1, 256, 0, stream>>>(partials, nb_nodes);
    scan_add_kernel<<<nb_nodes, 256, 0, stream>>>(row_ptr, partials, N);
    fill_kernel<<<nb_edges, 256, 0, stream>>>(src, dst, dinv, row_ptr, sorted_src, edge_w, E);

    // layer 1 GEMM (fp16 out)
    gemm1_kernel<<<(N + 31) / 32, 256, 0, stream>>>(x, W1, h1, N);

    // layer 1 aggregate + LN + ReLU + layer 2 GEMM (fused)
    gather1_fused_kernel<<<nb_wave_nodes, 256, 0, stream>>>(
        h1, dinv, row_ptr, counts, sorted_src, edge_w, b1, g1, beta1, W2, h3, N);

    // layer 2 aggregate + LN + ReLU + L2 (fused)
    gather2_fused_kernel<<<nb_wave_nodes, 256, 0, stream>>>(
        h3, dinv, row_ptr, counts, sorted_src, edge_w, b2, g2, beta2, out, N);
}

// Round 5
// 224.933 us; speedup vs baseline: 4.3311x; 1.1326x over previous
//
#include <hip/hip_runtime.h>
#include <hip/hip_fp16.h>

// GCN encoder on MI355X. CSR (counting sort by dst) + gather aggregation with
// fp16 activations, packed {src,w} edge records, unroll-8 gathers, and an
// MFMA (f16 in, fp32 accum) layer-1 GEMM. Epilogues fused.

#define K_DIM 128

typedef _Float16 f16x8 __attribute__((ext_vector_type(8)));
typedef _Float16 f16x4 __attribute__((ext_vector_type(4)));
typedef float f32x4 __attribute__((ext_vector_type(4)));

// ---------- CSR build ----------
__global__ __launch_bounds__(256) void hist_kernel(const int* __restrict__ dst,
                                                   int* counts, int E) {
    int i = blockIdx.x * 256 + threadIdx.x;
    if (i < E) atomicAdd(&counts[dst[i]], 1);
}

// block-local exclusive scan of counts -> row_ptr; partials[b] = block total.
// Also computes dinv (degree includes +1 self-loop).
__global__ __launch_bounds__(256) void scan_block_kernel(const int* __restrict__ counts,
                                                         int* row_ptr, int* partials,
                                                         float* dinv, int N) {
    __shared__ int sm[256];
    int t = threadIdx.x;
    int i = blockIdx.x * 256 + t;
    int v = (i < N) ? counts[i] : 0;
    if (i < N) dinv[i] = rsqrtf((float)(v + 1));
    sm[t] = v;
    __syncthreads();
    for (int off = 1; off < 256; off <<= 1) {
        int add = (t >= off) ? sm[t - off] : 0;
        __syncthreads();
        sm[t] += add;
        __syncthreads();
    }
    if (i < N) row_ptr[i] = sm[t] - v;  // block-local exclusive
    if (t == 255) partials[blockIdx.x] = sm[255];
}

__global__ __launch_bounds__(256) void scan_partials_kernel(int* partials, int NB) {
    __shared__ int sm[256];
    int t = threadIdx.x;
    int v = (t < NB) ? partials[t] : 0;
    sm[t] = v;
    __syncthreads();
    for (int off = 1; off < 256; off <<= 1) {
        int add = (t >= off) ? sm[t - off] : 0;
        __syncthreads();
        sm[t] += add;
        __syncthreads();
    }
    if (t < NB) partials[t] = sm[t] - v;  // exclusive
}

// fill: row_ptr[d] is a block-local cursor; global pos = cursor + partials[d>>8].
// Edge record packs {src, dinv[s]*dinv[d]}.
__global__ __launch_bounds__(256) void fill_kernel(const int* __restrict__ src,
                                                   const int* __restrict__ dst,
                                                   const float* __restrict__ dinv,
                                                   int* row_ptr,
                                                   const int* __restrict__ partials,
                                                   int2* edges, int E) {
    int i = blockIdx.x * 256 + threadIdx.x;
    if (i < E) {
        int d = dst[i];
        int s = src[i];
        int pos = atomicAdd(&row_ptr[d], 1) + partials[d >> 8];
        edges[pos] = make_int2(s, __float_as_int(dinv[s] * dinv[d]));
    }
}

// ---------- W1 -> W1^T fp16 (WT[j][k]) ----------
__global__ __launch_bounds__(256) void wt_prep_kernel(const float* __restrict__ W1,
                                                      _Float16* __restrict__ WT) {
    int idx = blockIdx.x * 256 + threadIdx.x;
    if (idx < 128 * 128) {
        int k = idx >> 7, j = idx & 127;
        WT[j * 128 + k] = (_Float16)W1[idx];
    }
}

// ---------- GEMM1 (MFMA): H = X @ W1, f16 out ----------
// Block: 64 rows x 128 cols, 4 waves (wave = 16 rows x 128 cols = 8 tiles).
__global__ __launch_bounds__(256) void gemm1_mfma_kernel(const float* __restrict__ X,
                                                         const _Float16* __restrict__ WT,
                                                         __half* __restrict__ H, int N) {
    __shared__ _Float16 As[64][136];  // +8 halves pad -> 2-way bank aliasing (free)

    int row0 = blockIdx.x * 64;
    {   // stage X tile as f16: thread -> row tid>>2, cols (tid&3)*32 .. +32
        int r = threadIdx.x >> 2;
        int c0 = (threadIdx.x & 3) * 32;
        int row = row0 + r;
        if (row < N) {
            const float4* srcp = (const float4*)(X + (size_t)row * 128 + c0);
#pragma unroll
            for (int i = 0; i < 8; ++i) {
                float4 v = srcp[i];
                f16x4 h = {(_Float16)v.x, (_Float16)v.y, (_Float16)v.z, (_Float16)v.w};
                *(f16x4*)&As[r][c0 + 4 * i] = h;
            }
        } else {
            f16x4 z = {};
#pragma unroll
            for (int i = 0; i < 8; ++i) *(f16x4*)&As[r][c0 + 4 * i] = z;
        }
    }
    __syncthreads();

    int wave = threadIdx.x >> 6;
    int lane = threadIdx.x & 63;
    int l15 = lane & 15;
    int k0 = (lane >> 4) * 8;
    int arow = wave * 16 + l15;

    f32x4 acc[8] = {};
#pragma unroll
    for (int ks = 0; ks < 4; ++ks) {
        f16x8 a = *(const f16x8*)&As[arow][ks * 32 + k0];
#pragma unroll
        for (int t = 0; t < 8; ++t) {
            f16x8 b = *(const f16x8*)(WT + (size_t)(t * 16 + l15) * 128 + ks * 32 + k0);
            acc[t] = __builtin_amdgcn_mfma_f32_16x16x32_f16(a, b, acc[t], 0, 0, 0);
        }
    }

    // C/D layout: col = lane&15, row = (lane>>4)*4 + r
    int rbase = row0 + wave * 16 + (lane >> 4) * 4;
#pragma unroll
    for (int t = 0; t < 8; ++t) {
#pragma unroll
        for (int r = 0; r < 4; ++r) {
            int row = rbase + r;
            if (row < N) H[(size_t)row * 128 + t * 16 + l15] = __float2half(acc[t][r]);
        }
    }
}

// ---------- gather1 fused: agg(h1) -> +b1 -> LN -> ReLU -> @W2 -> h3 (fp16) ----------
__global__ __launch_bounds__(256) void gather1_fused_kernel(
    const __half* __restrict__ h1, const float* __restrict__ dinv,
    const int* __restrict__ row_ptr, const int* __restrict__ counts,
    const int* __restrict__ partials, const int2* __restrict__ edges,
    const float* __restrict__ b1, const float* __restrict__ g1,
    const float* __restrict__ beta1, const float* __restrict__ W2,
    __half* __restrict__ h3, int N) {
    __shared__ float lds[4][K_DIM];
    int wave = threadIdx.x >> 6;
    int lane = threadIdx.x & 63;
    int node = blockIdx.x * 4 + wave;
    if (node >= N) return;

    float dd = dinv[node];
    float2 acc = __half22float2(((const __half2*)(h1 + (size_t)node * 128))[lane]);
    acc.x *= dd * dd; acc.y *= dd * dd;

    int end = row_ptr[node] + partials[node >> 8];
    int beg = end - counts[node];
    int e = beg;
    for (; e + 8 <= end; e += 8) {
        int2 rc[8];
#pragma unroll
        for (int i = 0; i < 8; ++i) rc[i] = edges[e + i];
        __half2 v[8];
#pragma unroll
        for (int i = 0; i < 8; ++i)
            v[i] = ((const __half2*)(h1 + (size_t)rc[i].x * 128))[lane];
#pragma unroll
        for (int i = 0; i < 8; ++i) {
            float w = __int_as_float(rc[i].y);
            float2 f = __half22float2(v[i]);
            acc.x = fmaf(f.x, w, acc.x);
            acc.y = fmaf(f.y, w, acc.y);
        }
    }
    for (; e + 4 <= end; e += 4) {
        int2 rc[4];
#pragma unroll
        for (int i = 0; i < 4; ++i) rc[i] = edges[e + i];
        __half2 v[4];
#pragma unroll
        for (int i = 0; i < 4; ++i)
            v[i] = ((const __half2*)(h1 + (size_t)rc[i].x * 128))[lane];
#pragma unroll
        for (int i = 0; i < 4; ++i) {
            float w = __int_as_float(rc[i].y);
            float2 f = __half22float2(v[i]);
            acc.x = fmaf(f.x, w, acc.x);
            acc.y = fmaf(f.y, w, acc.y);
        }
    }
    for (; e < end; ++e) {
        int2 rc = edges[e];
        float w = __int_as_float(rc.y);
        float2 f = __half22float2(((const __half2*)(h1 + (size_t)rc.x * 128))[lane]);
        acc.x = fmaf(f.x, w, acc.x);
        acc.y = fmaf(f.y, w, acc.y);
    }

    // bias + LN + ReLU
    float2 bb = ((const float2*)b1)[lane];
    acc.x += bb.x; acc.y += bb.y;
    float s = acc.x + acc.y;
    for (int off = 32; off; off >>= 1) s += __shfl_xor(s, off);
    float mu = s * (1.0f / 128.0f);
    float dx = acc.x - mu, dy = acc.y - mu;
    float q = dx * dx + dy * dy;
    for (int off = 32; off; off >>= 1) q += __shfl_xor(q, off);
    float rstd = rsqrtf(q * (1.0f / 128.0f) + 1e-5f);
    float2 gg = ((const float2*)g1)[lane];
    float2 be = ((const float2*)beta1)[lane];
    float ox = fmaxf(fmaf(dx * rstd, gg.x, be.x), 0.0f);
    float oy = fmaxf(fmaf(dy * rstd, gg.y, be.y), 0.0f);

    // 128x64 matvec via LDS broadcast; lane owns output col = lane
    ((float2*)&lds[wave][0])[lane] = make_float2(ox, oy);
    float o = 0.0f;
#pragma unroll 8
    for (int k = 0; k < K_DIM; k += 4) {
        float4 vv = *(const float4*)&lds[wave][k];
        o = fmaf(vv.x, W2[(size_t)(k + 0) * 64 + lane], o);
        o = fmaf(vv.y, W2[(size_t)(k + 1) * 64 + lane], o);
        o = fmaf(vv.z, W2[(size_t)(k + 2) * 64 + lane], o);
        o = fmaf(vv.w, W2[(size_t)(k + 3) * 64 + lane], o);
    }
    h3[(size_t)node * 64 + lane] = __float2half(o);
}

// ---------- gather2 fused: agg(h3) -> +b2 -> LN -> ReLU -> L2 -> out ----------
__global__ __launch_bounds__(256) void gather2_fused_kernel(
    const __half* __restrict__ h3, const float* __restrict__ dinv,
    const int* __restrict__ row_ptr, const int* __restrict__ counts,
    const int* __restrict__ partials, const int2* __restrict__ edges,
    const float* __restrict__ b2, const float* __restrict__ g2,
    const float* __restrict__ beta2, float* __restrict__ out, int N) {
    int wave = threadIdx.x >> 6;
    int lane = threadIdx.x & 63;
    int node = blockIdx.x * 4 + wave;
    if (node >= N) return;

    float dd = dinv[node];
    float acc = __half2float(h3[(size_t)node * 64 + lane]) * dd * dd;

    int end = row_ptr[node] + partials[node >> 8];
    int beg = end - counts[node];
    int e = beg;
    for (; e + 8 <= end; e += 8) {
        int2 rc[8];
#pragma unroll
        for (int i = 0; i < 8; ++i) rc[i] = edges[e + i];
        __half v[8];
#pragma unroll
        for (int i = 0; i < 8; ++i) v[i] = h3[(size_t)rc[i].x * 64 + lane];
#pragma unroll
        for (int i = 0; i < 8; ++i)
            acc = fmaf(__half2float(v[i]), __int_as_float(rc[i].y), acc);
    }
    for (; e + 4 <= end; e += 4) {
        int2 rc[4];
#pragma unroll
        for (int i = 0; i < 4; ++i) rc[i] = edges[e + i];
        __half v[4];
#pragma unroll
        for (int i = 0; i < 4; ++i) v[i] = h3[(size_t)rc[i].x * 64 + lane];
#pragma unroll
        for (int i = 0; i < 4; ++i)
            acc = fmaf(__half2float(v[i]), __int_as_float(rc[i].y), acc);
    }
    for (; e < end; ++e) {
        int2 rc = edges[e];
        acc = fmaf(__half2float(h3[(size_t)rc.x * 64 + lane]), __int_as_float(rc.y), acc);
    }

    float v = acc + b2[lane];
    float s = v;
    for (int off = 32; off; off >>= 1) s += __shfl_xor(s, off);
    float mu = s * (1.0f / 64.0f);
    float d = v - mu;
    float q = d * d;
    for (int off = 32; off; off >>= 1) q += __shfl_xor(q, off);
    float rstd = rsqrtf(q * (1.0f / 64.0f) + 1e-5f);
    float o = fmaxf(fmaf(d * rstd, g2[lane], beta2[lane]), 0.0f);
    float q2 = o * o;
    for (int off = 32; off; off >>= 1) q2 += __shfl_xor(q2, off);
    float nrm = sqrtf(q2);
    out[(size_t)node * 64 + lane] = o / fmaxf(nrm, 1e-12f);
}

extern "C" void kernel_launch(void* const* d_in, const int* in_sizes, int n_in,
                              void* d_out, int out_size, void* d_ws, size_t ws_size,
                              hipStream_t stream) {
    const float* x     = (const float*)d_in[0];
    const int*   ei    = (const int*)d_in[1];
    const float* W1    = (const float*)d_in[2];
    const float* b1    = (const float*)d_in[3];
    const float* g1    = (const float*)d_in[4];
    const float* beta1 = (const float*)d_in[5];
    const float* W2    = (const float*)d_in[6];
    const float* b2    = (const float*)d_in[7];
    const float* g2    = (const float*)d_in[8];
    const float* beta2 = (const float*)d_in[9];

    const int N = in_sizes[0] / 128;
    const int E = in_sizes[1] / 2;
    const int* src = ei;       // edge_index[0]
    const int* dst = ei + E;   // edge_index[1]
    float* out = (float*)d_out;

    // Workspace (~26.5 MB)
    char* p = (char*)d_ws;
    auto alloc = [&](size_t bytes) { char* r = p; p += (bytes + 255) & ~(size_t)255; return r; };
    int*      counts   = (int*)alloc((size_t)N * 4);
    int*      row_ptr  = (int*)alloc((size_t)N * 4);
    int*      partials = (int*)alloc(256 * 4);
    float*    dinv     = (float*)alloc((size_t)N * 4);
    int2*     edges    = (int2*)alloc((size_t)E * 8);
    _Float16* WT       = (_Float16*)alloc(128 * 128 * 2);
    __half*   h1       = (__half*)alloc((size_t)N * 128 * 2);
    __half*   h3       = (__half*)alloc((size_t)N * 64 * 2);

    const int nb_nodes = (N + 255) / 256;
    const int nb_edges = (E + 255) / 256;
    const int nb_wave_nodes = (N + 3) / 4;

    // CSR build + dinv + packed edge records
    hipMemsetAsync(counts, 0, (size_t)N * 4, stream);
    hist_kernel<<<nb_edges, 256, 0, stream>>>(dst, counts, E);
    scan_block_kernel<<<nb_nodes, 256, 0, stream>>>(counts, row_ptr, partials, dinv, N);
    scan_partials_kernel<<<1, 256, 0, stream>>>(partials, nb_nodes);
    fill_kernel<<<nb_edges, 256, 0, stream>>>(src, dst, dinv, row_ptr, partials, edges, E);

    // layer 1 GEMM (MFMA, f16 out)
    wt_prep_kernel<<<64, 256, 0, stream>>>(W1, WT);
    gemm1_mfma_kernel<<<(N + 63) / 64, 256, 0, stream>>>(x, WT, h1, N);

    // layer 1 aggregate + LN + ReLU + layer 2 GEMM (fused)
    gather1_fused_kernel<<<nb_wave_nodes, 256, 0, stream>>>(
        h1, dinv, row_ptr, counts, partials, edges, b1, g1, beta1, W2, h3, N);

    // layer 2 aggregate + LN + ReLU + L2 (fused)
    gather2_fused_kernel<<<nb_wave_nodes, 256, 0, stream>>>(
        h3, dinv, row_ptr, counts, partials, edges, b2, g2, beta2, out, N);
}